// Round 4
// baseline (551.118 us; speedup 1.0000x reference)
//
#include <hip/hip_runtime.h>

// Izhikevich neuron scan. x: [B=16, C=64, N=1024, T=32] f32, T contiguous.
// 1M independent neurons, 32-step sequential recurrence each.
//
// R3-R5 post-mortem: the LDS-transpose skeleton (coalesced loads -> ds
// transpose -> compute -> ds transpose -> coalesced stores) is structurally
// latency-bound and occupancy-capped. Single-wave WGs top out at ~16 WGs/CU
// and 9216 B LDS binds at the same 17 -> occupancy can never exceed ~50%
// (measured 28%). Three rounds of software-pipelining attempts (prefetch regs,
// sched_barrier(0) pins, lgkm-only waitcnts) all failed to survive the
// backend scheduler (VGPR_Count stuck at 44 = prefetch sunk to use) and all
// landed at 80-85 us with every pipe idle (VALU 18%, HBM 30%, MfmaUtil 0).
//
// R6: no LDS at all. One thread = one neuron; its 32 timesteps are its own
// contiguous 128 B -> 8 x dwordx4 loads at 128-B lane stride. Per-instruction
// coalescing is worse (64 lanes, 64 distinct lines) but the wave's 8 loads
// jointly consume a contiguous 8 KB -- every line fully used, HBM/L2 traffic
// unchanged; cost moves to L1 transactions, which overlap across waves.
// Occupancy does the latency hiding that pipelining couldn't:
//   zero LDS + TPB=256 -> 8 blocks/CU = 32 waves/CU = 100% occupancy cap,
//   32 waves x 8 KB outstanding per CU >> Little's-law requirement.
// No barriers, no fences, no inter-thread communication of any kind.
// Stores are nontemporal (output never re-read; keeps L3 for the input);
// the wave's 8 stores jointly cover full 128-B lines -> L2 write-combines.
//
// Numerics: bit-exact f32 replication of the reference (contract off,
// left-assoc order, literal spike-blend). No staging, bits untouched.

#define T_STEPS 32
#define TPB 256         // 4 independent waves/block; 8 blocks/CU = 32 waves/CU

// Native clang vector: accepted by __builtin_nontemporal_store
// (HIP float4 is a class and is rejected).
typedef float vf4 __attribute__((ext_vector_type(4)));

__global__ __launch_bounds__(TPB) void izhikevich_kernel(
    const float* __restrict__ x,
    const float* __restrict__ pa,
    const float* __restrict__ pb,
    const float* __restrict__ pc,
    const float* __restrict__ pd,
    float* __restrict__ out)
{
#pragma clang fp contract(off)
    const size_t neuron = (size_t)blockIdx.x * TPB + threadIdx.x;
    const float* __restrict__ xp = x + neuron * T_STEPS;      // 128-B aligned
    float* __restrict__ op = out + neuron * T_STEPS;

    const float a = pa[0];
    const float b = pb[0];
    const float c = pc[0];
    const float d = pd[0];

    // ---- Load own 32 timesteps: 8 x dwordx4, all issued before first use.
    // Backend inserts counted vmcnt waits (consume k -> vmcnt(7-k)): only
    // the first consumption exposes latency, and 32 waves/CU hide it.
    vf4 xv[8];
#pragma unroll
    for (int k = 0; k < 8; ++k)
        xv[k] = *reinterpret_cast<const vf4*>(xp + 4 * k);

    // ---- Recurrence (bit-exact), spikes packed into 8 float4s -------------
    float v = 0.0f;
    float u = 0.0f;
    vf4 sp[8];
#pragma unroll
    for (int j = 0; j < 8; ++j) {
#pragma unroll
        for (int i = 0; i < 4; ++i) {
            const float xt = xv[j][i];
            // dv = 0.04*v*v + 5.0*v + 140.0 - u + x_t  (left-assoc, no fma)
            const float t1 = (0.04f * v) * v;
            const float t2 = 5.0f * v;
            const float dv = (((t1 + t2) + 140.0f) - u) + xt;
            v = v + dv;                          // DT = 1.0 exact
            const float du = a * ((b * v) - u);
            u = u + du;
            const float spike = (v >= 30.0f) ? 1.0f : 0.0f;
            const float oms = 1.0f - spike;
            v = (v * oms) + (c * spike);         // exact for spike in {0,1}
            u = u + (d * spike);
            sp[j][i] = spike;
        }
    }

    // ---- Store own 32 spikes: 8 x dwordx4 nontemporal, fire-and-forget ----
#pragma unroll
    for (int k = 0; k < 8; ++k)
        __builtin_nontemporal_store(sp[k], reinterpret_cast<vf4*>(op + 4 * k));
}

extern "C" void kernel_launch(void* const* d_in, const int* in_sizes, int n_in,
                              void* d_out, int out_size, void* d_ws, size_t ws_size,
                              hipStream_t stream) {
    const float* x  = (const float*)d_in[0];
    const float* pa = (const float*)d_in[1];
    const float* pb = (const float*)d_in[2];
    const float* pc = (const float*)d_in[3];
    const float* pd = (const float*)d_in[4];
    float* out = (float*)d_out;

    const int n_neurons = in_sizes[0] / T_STEPS;   // 1,048,576
    const int grid = n_neurons / TPB;              // 4096 (exact)

    izhikevich_kernel<<<grid, TPB, 0, stream>>>(x, pa, pb, pc, pd, out);
}

// Round 5
// 245.328 us; speedup vs baseline: 2.2465x; 2.2465x over previous
//
#include <hip/hip_runtime.h>
#include <stdint.h>

// Izhikevich neuron scan. x: [B=16, C=64, N=1024, T=32] f32, T contiguous.
// 1M independent neurons, 32-step sequential recurrence each.
//
// R6 post-mortem: strided per-lane access (64 lines/instr) is ~10x slower
// through the TA than coalesced (400 us, HBM 12%); NT 16-B scatter broke L2
// write-combine (WRITE 131->304 MB). Coalesced access + transpose it is.
// R3-R5 post-mortem: VGPR-staged loads get sunk by the scheduler (VGPR=44
// across all variants); every tile re-exposed full latency => 80-85 us.
//
// R7: global_load_lds + counted vmcnt (guide T4 / Common-mistake #1).
//  - Staging via __builtin_amdgcn_global_load_lds width=16: no VGPR dest,
//    nothing to sink. Double-buffered 8 KB tiles, depth-1 prefetch.
//  - vmcnt retires IN ISSUE ORDER (m135), so counted waits are exact:
//    steady-state queue at tile i's wait = [loads_i | S_{i-2} | loads_{i+1}
//    | S_{i-1}] -> vmcnt(24) guarantees loads_i done, leaves the prefetch
//    and newest stores in flight. Never vmcnt(0) in the loop.
//  - gload_lds dest must be linear (lane x 16B), so the bank swizzle is
//    applied on the GLOBAL source (m173): slot s holds float4 #sigma(s),
//    sigma(m) = m ^ ((m>>3)&7). Per-lane fetch offset = (t ^ (t>>3))*16.
//    Read back: thread t, j -> slot 8t + (j^(t&7)): uniform 8 slots/bank
//    = the b128 minimum (8 phases), no 32-way column conflict.
//  - Output transpose WITHOUT LDS: thread t packs its 32 spikes into one
//    uint32; store k pulls lane 8k+(t>>3)'s word via ds_bpermute (4 B/lane
//    instead of a 128 B LDS round-trip), expands 4 bits -> float4, stores
//    nontemporal (full-line coalesced, so NT is safe; keeps L3 for x).
//  - LDS 16 KB/block -> 10 blocks/CU cap; grid 2048 = 8 blocks/CU fully
//    resident, each wave perpetually holds one 8 KB tile in flight.
//
// Numerics: bit-exact f32 replication (contract off, left-assoc, literal
// spike-blend). Spike floats regenerated as exact 1.0f/0.0f.

#define T_STEPS 32
#define TPB 64
#define NT 8
#define TILE_F 2048       // floats per tile (64 neurons x 32 steps) = 8 KB

typedef float vf4 __attribute__((ext_vector_type(4)));

// s_waitcnt simm16 (gfx9): vmcnt[3:0]|[15:14], expcnt[6:4], lgkmcnt[11:8]
#define WVM8   0x0F78     // vmcnt(8),  lgkm=15, exp=7
#define WVM16  0x4F70     // vmcnt(16)
#define WVM24  0x4F78     // vmcnt(24)
#define WLGKM0 0xC07F     // lgkmcnt(0), vmcnt=63, exp=7

typedef const __attribute__((address_space(1))) unsigned int* gas_t;
typedef __attribute__((address_space(3))) unsigned int* las_t;

// One pipeline step. WIMM = compile-time waitcnt imm; BSEL/TILE may be
// runtime (rolled middle loop). Loop vars jj/ii/kk avoid capture clashes.
#define STEP(WIMM, BSEL, TILE, DOSTAGE) do {                                  \
    __builtin_amdgcn_s_waitcnt(WIMM);                                         \
    __builtin_amdgcn_sched_barrier(0);                                        \
    const float* lb = &buf[(BSEL) * TILE_F];                                  \
    vf4 xs[8];                                                                \
    _Pragma("unroll")                                                         \
    for (int jj = 0; jj < 8; ++jj)                                            \
        xs[jj] = *reinterpret_cast<const vf4*>(                               \
            lb + 32 * t + ((jj ^ (t & 7)) << 2));                             \
    __builtin_amdgcn_s_waitcnt(WLGKM0);   /* reads landed; VMEM untouched */  \
    __builtin_amdgcn_sched_barrier(0);                                        \
    if (DOSTAGE) stage((BSEL), (TILE) + 2);                                   \
    float v = 0.0f, u = 0.0f;                                                 \
    unsigned pk = 0u;                                                         \
    _Pragma("unroll")                                                         \
    for (int jj = 0; jj < 8; ++jj) {                                          \
        _Pragma("unroll")                                                     \
        for (int ii = 0; ii < 4; ++ii) {                                      \
            const float xt = xs[jj][ii];                                      \
            const float t1 = (0.04f * v) * v;                                 \
            const float t2 = 5.0f * v;                                        \
            const float dv = (((t1 + t2) + 140.0f) - u) + xt;                 \
            v = v + dv;                         /* DT = 1.0 exact */          \
            const float du = a * ((b * v) - u);                               \
            u = u + du;                                                       \
            const bool sb = (v >= 30.0f);                                     \
            const float spike = sb ? 1.0f : 0.0f;                             \
            pk |= sb ? (1u << (4 * jj + ii)) : 0u;                            \
            const float oms = 1.0f - spike;                                   \
            v = (v * oms) + (c * spike);        /* exact: spike in {0,1} */   \
            u = u + (d * spike);                                              \
        }                                                                     \
    }                                                                         \
    vf4* op = reinterpret_cast<vf4*>(ob + (size_t)(TILE) * TILE_F);           \
    _Pragma("unroll")                                                         \
    for (int kk = 0; kk < 8; ++kk) {                                          \
        const int wk = __builtin_amdgcn_ds_bpermute(                          \
            32 * kk + ((t >> 3) << 2), (int)pk);                              \
        const unsigned nib = ((unsigned)wk >> ((t & 7) << 2)) & 0xFu;         \
        vf4 o;                                                                \
        o.x = (nib & 1u) ? 1.0f : 0.0f;                                       \
        o.y = (nib & 2u) ? 1.0f : 0.0f;                                       \
        o.z = (nib & 4u) ? 1.0f : 0.0f;                                       \
        o.w = (nib & 8u) ? 1.0f : 0.0f;                                       \
        __builtin_nontemporal_store(o, op + kk * 64 + t);                     \
    }                                                                         \
} while (0)

__global__ __launch_bounds__(TPB) void izhikevich_kernel(
    const float* __restrict__ x,
    const float* __restrict__ pa,
    const float* __restrict__ pb,
    const float* __restrict__ pc,
    const float* __restrict__ pd,
    float* __restrict__ out)
{
#pragma clang fp contract(off)
    __shared__ float buf[2 * TILE_F];           // 16384 B, no padding (gload_lds)

    const int t = threadIdx.x;
    const size_t base = (size_t)blockIdx.x * (NT * TILE_F);
    const float* __restrict__ xb = x + base;
    float* __restrict__ ob = out + base;

    const float a = pa[0];
    const float b = pb[0];
    const float c = pc[0];
    const float d = pd[0];

    // Per-lane swizzled source offset (floats): fetch float4 #(64k + t^(t>>3))
    // into linear slot 64k + t  ==>  slot s holds float4 #sigma(s).
    const int swz4 = ((t ^ (t >> 3)) << 2);

    const float* xbl = xb + swz4;
    auto stage = [&](int bsel, int tile) {
        const float* g = xbl + (size_t)tile * TILE_F;
        const float* l = &buf[bsel * TILE_F];
#pragma unroll
        for (int k = 0; k < 8; ++k)
            __builtin_amdgcn_global_load_lds((gas_t)(const void*)(g + k * 256),
                                             (las_t)(void*)(l + k * 256),
                                             16, 0, 0);
    };

    // Prologue: both buffers staged; 16 loads in flight.
    stage(0, 0);
    stage(1, 1);

    STEP(WVM8,  0, 0, true);                    // queue: [t0|t1]        -> 8
    STEP(WVM16, 1, 1, true);                    // [t1|t2,S0]            -> 16
#pragma unroll 1
    for (int i = 2; i <= NT - 2; ++i)           // [ti|S(i-2),t(i+1),S(i-1)]
        STEP(WVM24, (i & 1), i, (i + 2) < NT);  //                       -> 24
    STEP(WVM16, ((NT - 1) & 1), NT - 1, false); // [t7|S5,S6]            -> 16
}

extern "C" void kernel_launch(void* const* d_in, const int* in_sizes, int n_in,
                              void* d_out, int out_size, void* d_ws, size_t ws_size,
                              hipStream_t stream) {
    const float* x  = (const float*)d_in[0];
    const float* pa = (const float*)d_in[1];
    const float* pb = (const float*)d_in[2];
    const float* pc = (const float*)d_in[3];
    const float* pd = (const float*)d_in[4];
    float* out = (float*)d_out;

    const int n_neurons = in_sizes[0] / T_STEPS;    // 1,048,576
    const int grid = n_neurons / (TPB * NT);        // 2048 (exact)

    izhikevich_kernel<<<grid, TPB, 0, stream>>>(x, pa, pb, pc, pd, out);
}